// Round 4
// baseline (123.051 us; speedup 1.0000x reference)
//
#include <hip/hip_runtime.h>

// EdgeConsistencyLoss: mean((|∇edit| - |∇src|)^2) with Sobel 3x3, SAME zero pad.
// Shapes: [B=16, C=8, H=512, W=512] fp32 -> 128 independent 512x512 images.
//
// R1: occupancy 42->78% didn't help; halo bytes hurt.
// R2: sw-pipelined rows: 52.5us. VALU ~50% at graph time, HBM 44% -> instr-bound.
// R3: one wave = one full 512-wide row (8 cols/thread, 2xfloat4). Column halos
//     via __shfl (NO halo loads, no divergence). Wave-uniform boundary branches
//     (no mask mults). Streaming partial-sum state (fewer movs). 4 indep waves
//     per block. launch_bounds(256,4) pins VGPR<=128.

#define EPS 1e-8f

constexpr int W_DIM = 512;
constexpr int H_DIM = 512;
constexpr int NIMG  = 128;                     // B*C
constexpr int ROWS  = 16;                      // rows per wave
constexpr int WPB   = 4;                       // waves per block
constexpr int TPB   = 64 * WPB;                // 256
constexpr int BLK_ROWS = ROWS * WPB;           // 64
constexpr int BLKS_PER_IMG = H_DIM / BLK_ROWS; // 8
constexpr int NBLK  = NIMG * BLKS_PER_IMG;     // 1024
constexpr double TOTAL_ELEMS = 33554432.0;     // 16*8*512*512

__global__ __launch_bounds__(TPB, 4) void edge_loss_stage1(
    const float* __restrict__ src, const float* __restrict__ edt,
    float* __restrict__ partial)
{
    const int blk  = blockIdx.x;
    const int img  = blk / BLKS_PER_IMG;
    const int brow = (blk % BLKS_PER_IMG) * BLK_ROWS;
    const int wid  = threadIdx.x >> 6;
    const int lane = threadIdx.x & 63;
    const int r0   = brow + wid * ROWS;        // this wave's first output row
    const int c0   = lane * 8;                 // this thread's first column

    const float* sbase = src + (size_t)img * (H_DIM * W_DIM) + c0;
    const float* ebase = edt + (size_t)img * (H_DIM * W_DIM) + c0;

    // Streaming Sobel state (per col i, per tensor):
    //   P0 = a(r-2)+2a(r-1), P1 = a(r-1)   [a = x[w+1]-x[w-1]]
    //   B0 = b(r-2),         B1 = b(r-1)   [b = x[w-1]+2x[w]+x[w+1]]
    // On new row r:  gx(r-1)=P0+a(r); gy(r-1)=b(r)-B0;
    //                P0'=P1+2a(r); P1'=a(r); B0'=B1; B1'=b(r).
    float sP0[8], sP1[8], sB0[8], sB1[8];
    float eP0[8], eP1[8], eB0[8], eB1[8];
    float spA[8], epA[8], spB[8], epB[8];      // raw-row double buffers
    float acc = 0.f;

    auto issue = [&](int h, float* sp, float* ep) {
        int hc = h < 0 ? 0 : (h >= H_DIM ? H_DIM - 1 : h);
        const float* srow = sbase + (size_t)hc * W_DIM;
        const float* erow = ebase + (size_t)hc * W_DIM;
        float4 s0 = reinterpret_cast<const float4*>(srow)[0];
        float4 s1 = reinterpret_cast<const float4*>(srow)[1];
        float4 e0 = reinterpret_cast<const float4*>(erow)[0];
        float4 e1 = reinterpret_cast<const float4*>(erow)[1];
        sp[0]=s0.x; sp[1]=s0.y; sp[2]=s0.z; sp[3]=s0.w;
        sp[4]=s1.x; sp[5]=s1.y; sp[6]=s1.z; sp[7]=s1.w;
        ep[0]=e0.x; ep[1]=e0.y; ep[2]=e0.z; ep[3]=e0.w;
        ep[4]=e1.x; ep[5]=e1.y; ep[6]=e1.z; ep[7]=e1.w;
    };

    // Consume new row h (raw in sp/ep): emit output row h-1, update state.
    auto consume = [&](const float* sp, const float* ep, int h) {
        if (h < H_DIM) {   // h >= 1 always here; wave-uniform branch
            float spL = __shfl_up(sp[7], 1);  spL = lane ? spL : 0.f;
            float spR = __shfl_down(sp[0], 1); spR = (lane == 63) ? 0.f : spR;
            float epL = __shfl_up(ep[7], 1);  epL = lane ? epL : 0.f;
            float epR = __shfl_down(ep[0], 1); epR = (lane == 63) ? 0.f : epR;
            #pragma unroll
            for (int i = 0; i < 8; ++i) {
                float sm = (i == 0) ? spL : sp[i-1];
                float sq = (i == 7) ? spR : sp[i+1];
                float a  = sq - sm;
                float b  = sm + 2.f*sp[i] + sq;
                float gx = sP0[i] + a;
                sP0[i] = fmaf(2.f, a, sP1[i]);
                sP1[i] = a;
                float gy = b - sB0[i];
                sB0[i] = sB1[i]; sB1[i] = b;
                float es = __builtin_amdgcn_sqrtf(fmaf(gx, gx, fmaf(gy, gy, EPS)));

                float em = (i == 0) ? epL : ep[i-1];
                float eq = (i == 7) ? epR : ep[i+1];
                float a2 = eq - em;
                float b2 = em + 2.f*ep[i] + eq;
                float gx2 = eP0[i] + a2;
                eP0[i] = fmaf(2.f, a2, eP1[i]);
                eP1[i] = a2;
                float gy2 = b2 - eB0[i];
                eB0[i] = eB1[i]; eB1[i] = b2;
                float ee = __builtin_amdgcn_sqrtf(fmaf(gx2, gx2, fmaf(gy2, gy2, EPS)));

                float d = ee - es;
                acc = fmaf(d, d, acc);
            }
        } else {           // zero-pad row below the image
            #pragma unroll
            for (int i = 0; i < 8; ++i) {
                float gx = sP0[i];  sP0[i] = sP1[i]; sP1[i] = 0.f;
                float gy = -sB0[i]; sB0[i] = sB1[i]; sB1[i] = 0.f;
                float es = __builtin_amdgcn_sqrtf(fmaf(gx, gx, fmaf(gy, gy, EPS)));
                float gx2 = eP0[i];  eP0[i] = eP1[i]; eP1[i] = 0.f;
                float gy2 = -eB0[i]; eB0[i] = eB1[i]; eB1[i] = 0.f;
                float ee = __builtin_amdgcn_sqrtf(fmaf(gx2, gx2, fmaf(gy2, gy2, EPS)));
                float d = ee - es;
                acc = fmaf(d, d, acc);
            }
        }
    };

    // ---- Prologue: rows r0-1 and r0 into state; row r0+1 left in flight. ----
    issue(r0 - 1, spA, epA);
    issue(r0,     spB, epB);
    if (r0 > 0) {          // row r0-1 exists: P0=a, B0=b
        float spL = __shfl_up(spA[7], 1);  spL = lane ? spL : 0.f;
        float spR = __shfl_down(spA[0], 1); spR = (lane == 63) ? 0.f : spR;
        float epL = __shfl_up(epA[7], 1);  epL = lane ? epL : 0.f;
        float epR = __shfl_down(epA[0], 1); epR = (lane == 63) ? 0.f : epR;
        #pragma unroll
        for (int i = 0; i < 8; ++i) {
            float sm = (i == 0) ? spL : spA[i-1];
            float sq = (i == 7) ? spR : spA[i+1];
            sP0[i] = sq - sm;
            sB0[i] = sm + 2.f*spA[i] + sq;
            float em = (i == 0) ? epL : epA[i-1];
            float eq = (i == 7) ? epR : epA[i+1];
            eP0[i] = eq - em;
            eB0[i] = em + 2.f*epA[i] + eq;
        }
    } else {
        #pragma unroll
        for (int i = 0; i < 8; ++i) { sP0[i]=0.f; sB0[i]=0.f; eP0[i]=0.f; eB0[i]=0.f; }
    }
    {   // row r0 (always in range): P0 += 2a, P1 = a, B1 = b
        float spL = __shfl_up(spB[7], 1);  spL = lane ? spL : 0.f;
        float spR = __shfl_down(spB[0], 1); spR = (lane == 63) ? 0.f : spR;
        float epL = __shfl_up(epB[7], 1);  epL = lane ? epL : 0.f;
        float epR = __shfl_down(epB[0], 1); epR = (lane == 63) ? 0.f : epR;
        #pragma unroll
        for (int i = 0; i < 8; ++i) {
            float sm = (i == 0) ? spL : spB[i-1];
            float sq = (i == 7) ? spR : spB[i+1];
            float a  = sq - sm;
            sP0[i] = fmaf(2.f, a, sP0[i]);
            sP1[i] = a;
            sB1[i] = sm + 2.f*spB[i] + sq;
            float em = (i == 0) ? epL : epB[i-1];
            float eq = (i == 7) ? epR : epB[i+1];
            float a2 = eq - em;
            eP0[i] = fmaf(2.f, a2, eP0[i]);
            eP1[i] = a2;
            eB1[i] = em + 2.f*epB[i] + eq;
        }
    }
    issue(r0 + 1, spA, epA);

    // ---- Main loop: 2 new rows per iteration, prefetch distance 1 row. ----
    for (int r = r0 + 1; r <= r0 + ROWS; r += 2) {
        issue(r + 1, spB, epB);
        consume(spA, epA, r);
        if (r + 2 <= r0 + ROWS) issue(r + 2, spA, epA);
        consume(spB, epB, r + 1);
    }

    // ---- Reduction: wave shuffle, then LDS across the 4 waves. ----
    #pragma unroll
    for (int off = 32; off > 0; off >>= 1)
        acc += __shfl_down(acc, off);
    __shared__ float wsum[WPB];
    if (lane == 0) wsum[wid] = acc;
    __syncthreads();
    if (threadIdx.x == 0) {
        float tot = 0.f;
        #pragma unroll
        for (int i = 0; i < WPB; ++i) tot += wsum[i];
        partial[blk] = tot;
    }
}

__global__ __launch_bounds__(256) void edge_loss_stage2(
    const float* __restrict__ partial, float* __restrict__ out, int nparts)
{
    double acc = 0.0;
    for (int i = threadIdx.x; i < nparts; i += 256)
        acc += (double)partial[i];
    #pragma unroll
    for (int off = 32; off > 0; off >>= 1)
        acc += __shfl_down(acc, off);
    __shared__ double wsum[4];
    const int wid  = threadIdx.x >> 6;
    const int lane = threadIdx.x & 63;
    if (lane == 0) wsum[wid] = acc;
    __syncthreads();
    if (threadIdx.x == 0) {
        double t = 0.0;
        #pragma unroll
        for (int i = 0; i < 4; ++i) t += wsum[i];
        out[0] = (float)(t / TOTAL_ELEMS);
    }
}

extern "C" void kernel_launch(void* const* d_in, const int* in_sizes, int n_in,
                              void* d_out, int out_size, void* d_ws, size_t ws_size,
                              hipStream_t stream) {
    const float* src = (const float*)d_in[0];  // source_latent
    const float* edt = (const float*)d_in[1];  // edited_latent
    // d_in[2]/d_in[3] are the fixed Sobel kernels; baked into the math above
    // (flip-sign ambiguity is irrelevant under the magnitude).
    float* out     = (float*)d_out;
    float* partial = (float*)d_ws;             // NBLK floats = 4 KB, overwritten every call

    edge_loss_stage1<<<dim3(NBLK), dim3(TPB), 0, stream>>>(src, edt, partial);
    edge_loss_stage2<<<dim3(1), dim3(256), 0, stream>>>(partial, out, NBLK);
}

// Round 5
// 50.884 us; speedup vs baseline: 2.4183x; 2.4183x over previous
//
#include <hip/hip_runtime.h>

// EdgeConsistencyLoss: mean((|∇edit| - |∇src|)^2) with Sobel 3x3, SAME zero pad.
// [B=16, C=8, H=512, W=512] fp32 -> 128 independent 512x512 images.
//
// R1: occupancy 42->78% didn't help; halo bytes hurt. Time ~ HBM bytes.
// R2: sw-pipeline depth-1: 52.5us, 44 VGPR. Best so far.
// R3: 8 cols/thread + launch_bounds(256,4): compiler capped at 64 VGPR ->
//     SPILLED (WRITE_SIZE 174MB!) -> 123us. Reverted.
// R4: R2 shape (ROWS=32, TPB=128, 4 cols/thread) + shfl column halos (no
//     per-thread halo loads; 1 exec-masked seam load/tensor/row) + prefetch
//     depth 2 (4 named buffers). No launch_bounds min-waves: let VGPR ~100.

#define EPS 1e-8f

constexpr int W_DIM  = 512;
constexpr int H_DIM  = 512;
constexpr int NIMG   = 128;           // B*C
constexpr int ROWS   = 32;            // rows per block chunk (multiple of 4)
constexpr int CHUNKS = H_DIM / ROWS;  // 16
constexpr int TPB    = 128;           // 2 waves; block covers full 512-px width
constexpr int NBLK   = NIMG * CHUNKS; // 2048
constexpr double TOTAL_ELEMS = 33554432.0; // 16*8*512*512

struct RowBuf { float4 s, e; float ss, es; };

__global__ __launch_bounds__(TPB) void edge_loss_stage1(
    const float* __restrict__ src, const float* __restrict__ edt,
    float* __restrict__ partial)
{
    const int blk  = blockIdx.x;
    const int img  = blk / CHUNKS;
    const int r0   = (blk % CHUNKS) * ROWS;
    const int wv   = threadIdx.x >> 6;
    const int lane = threadIdx.x & 63;
    const int c0   = threadIdx.x * 4;   // wave0: cols 0..255, wave1: 256..511

    const float* simg = src + (size_t)img * (H_DIM * W_DIM);
    const float* eimg = edt + (size_t)img * (H_DIM * W_DIM);

    // Wave-seam: wave0 lane63 needs col 256; wave1 lane0 needs col 255.
    // Image edges (col -1, col 512) are zero-pad; seam reg stays 0 there.
    const bool seam_active = (wv == 0) ? (lane == 63) : (lane == 0);
    const int  seamcol     = (wv == 0) ? 256 : 255;

    // Streaming Sobel state per column i (P: gx partials, Q: b history):
    //   a(h) = x[h,w+1]-x[h,w-1];  b(h) = x[h,w-1]+2x[h,w]+x[h,w+1]
    //   gx(h-1) = P0 + a(h);  gy(h-1) = b(h) - Q0
    //   P0' = P1 + 2a(h); P1' = a(h); Q0' = Q1; Q1' = b(h)
    float sP0[4], sP1[4], sQ0[4], sQ1[4];
    float eP0[4], eP1[4], eQ0[4], eQ1[4];
    float acc = 0.f;

    auto issue = [&](int h, RowBuf& rb) {
        int hc = h < 0 ? 0 : (h >= H_DIM ? H_DIM - 1 : h);
        const float* srow = simg + (size_t)hc * W_DIM;
        const float* erow = eimg + (size_t)hc * W_DIM;
        rb.s = *reinterpret_cast<const float4*>(srow + c0);
        rb.e = *reinterpret_cast<const float4*>(erow + c0);
        rb.ss = 0.f; rb.es = 0.f;
        if (seam_active) { rb.ss = srow[seamcol]; rb.es = erow[seamcol]; }
    };

    // Extend the 4 raw pixels to 6 with halos from lane neighbors / seam regs.
    auto halos = [&](const RowBuf& rb, float sp[6], float ep[6]) {
        float slT = __shfl_up(rb.s.w, 1);
        float srT = __shfl_down(rb.s.x, 1);
        float elT = __shfl_up(rb.e.w, 1);
        float erT = __shfl_down(rb.e.x, 1);
        sp[0] = (lane == 0)  ? rb.ss : slT;   // wave0 lane0: ss==0 (image edge)
        sp[5] = (lane == 63) ? rb.ss : srT;   // wave1 lane63: ss==0
        ep[0] = (lane == 0)  ? rb.es : elT;
        ep[5] = (lane == 63) ? rb.es : erT;
        sp[1]=rb.s.x; sp[2]=rb.s.y; sp[3]=rb.s.z; sp[4]=rb.s.w;
        ep[1]=rb.e.x; ep[2]=rb.e.y; ep[3]=rb.e.z; ep[4]=rb.e.w;
    };

    // Consume raw row h: emit output row h-1, advance state.
    auto consume = [&](const RowBuf& rb, int h) {
        if (h < H_DIM) {                      // wave-uniform branch
            float sp[6], ep[6];
            halos(rb, sp, ep);
            #pragma unroll
            for (int i = 0; i < 4; ++i) {
                float a  = sp[i+2] - sp[i];
                float b  = sp[i] + 2.f*sp[i+1] + sp[i+2];
                float gx = sP0[i] + a;
                float gy = b - sQ0[i];
                sP0[i] = fmaf(2.f, a, sP1[i]); sP1[i] = a;
                sQ0[i] = sQ1[i]; sQ1[i] = b;
                float es = __builtin_amdgcn_sqrtf(fmaf(gx, gx, fmaf(gy, gy, EPS)));
                float a2  = ep[i+2] - ep[i];
                float b2  = ep[i] + 2.f*ep[i+1] + ep[i+2];
                float gx2 = eP0[i] + a2;
                float gy2 = b2 - eQ0[i];
                eP0[i] = fmaf(2.f, a2, eP1[i]); eP1[i] = a2;
                eQ0[i] = eQ1[i]; eQ1[i] = b2;
                float ee = __builtin_amdgcn_sqrtf(fmaf(gx2, gx2, fmaf(gy2, gy2, EPS)));
                float d = ee - es;
                acc = fmaf(d, d, acc);
            }
        } else {                              // zero-pad row below image
            #pragma unroll
            for (int i = 0; i < 4; ++i) {
                float gx = sP0[i], gy = -sQ0[i];
                sP0[i] = sP1[i]; sP1[i] = 0.f; sQ0[i] = sQ1[i]; sQ1[i] = 0.f;
                float es = __builtin_amdgcn_sqrtf(fmaf(gx, gx, fmaf(gy, gy, EPS)));
                float gx2 = eP0[i], gy2 = -eQ0[i];
                eP0[i] = eP1[i]; eP1[i] = 0.f; eQ0[i] = eQ1[i]; eQ1[i] = 0.f;
                float ee = __builtin_amdgcn_sqrtf(fmaf(gx2, gx2, fmaf(gy2, gy2, EPS)));
                float d = ee - es;
                acc = fmaf(d, d, acc);
            }
        }
    };

    // ---- Prologue: 4 rows in flight before first consume. ----
    RowBuf bA0, bA1, bB0, bB1;
    issue(r0 - 1, bA0);
    issue(r0,     bA1);
    issue(r0 + 1, bB0);
    issue(r0 + 2, bB1);

    if (r0 > 0) {          // row r0-1 exists: P0 = a, Q0 = b
        float sp[6], ep[6];
        halos(bA0, sp, ep);
        #pragma unroll
        for (int i = 0; i < 4; ++i) {
            sP0[i] = sp[i+2] - sp[i];
            sQ0[i] = sp[i] + 2.f*sp[i+1] + sp[i+2];
            eP0[i] = ep[i+2] - ep[i];
            eQ0[i] = ep[i] + 2.f*ep[i+1] + ep[i+2];
        }
    } else {
        #pragma unroll
        for (int i = 0; i < 4; ++i) { sP0[i]=0.f; sQ0[i]=0.f; eP0[i]=0.f; eQ0[i]=0.f; }
    }
    {   // row r0: P0 += 2a, P1 = a, Q1 = b
        float sp[6], ep[6];
        halos(bA1, sp, ep);
        #pragma unroll
        for (int i = 0; i < 4; ++i) {
            float a  = sp[i+2] - sp[i];
            sP0[i] = fmaf(2.f, a, sP0[i]); sP1[i] = a;
            sQ1[i] = sp[i] + 2.f*sp[i+1] + sp[i+2];
            float a2 = ep[i+2] - ep[i];
            eP0[i] = fmaf(2.f, a2, eP0[i]); eP1[i] = a2;
            eQ1[i] = ep[i] + 2.f*ep[i+1] + ep[i+2];
        }
    }

    // ---- Main loop: 4 rows per iteration, A/B pair rotation, depth ~2. ----
    int h = r0 + 1;
    #pragma unroll 1
    for (int k = 0; k < ROWS / 4; ++k, h += 4) {
        if (h + 2 <= r0 + ROWS) issue(h + 2, bA0);
        if (h + 3 <= r0 + ROWS) issue(h + 3, bA1);
        consume(bB0, h);
        consume(bB1, h + 1);
        if (h + 4 <= r0 + ROWS) issue(h + 4, bB0);
        if (h + 5 <= r0 + ROWS) issue(h + 5, bB1);
        consume(bA0, h + 2);
        consume(bA1, h + 3);
    }

    // ---- Reduction: wave shuffle, then LDS across the 2 waves. ----
    #pragma unroll
    for (int off = 32; off > 0; off >>= 1)
        acc += __shfl_down(acc, off);
    __shared__ float wsum[TPB / 64];
    if (lane == 0) wsum[wv] = acc;
    __syncthreads();
    if (threadIdx.x == 0) {
        float tot = 0.f;
        #pragma unroll
        for (int i = 0; i < TPB / 64; ++i) tot += wsum[i];
        partial[blk] = tot;
    }
}

__global__ __launch_bounds__(256) void edge_loss_stage2(
    const float* __restrict__ partial, float* __restrict__ out, int nparts)
{
    double acc = 0.0;
    for (int i = threadIdx.x; i < nparts; i += 256)
        acc += (double)partial[i];
    #pragma unroll
    for (int off = 32; off > 0; off >>= 1)
        acc += __shfl_down(acc, off);
    __shared__ double wsum[4];
    const int wid  = threadIdx.x >> 6;
    const int lane = threadIdx.x & 63;
    if (lane == 0) wsum[wid] = acc;
    __syncthreads();
    if (threadIdx.x == 0) {
        double t = 0.0;
        #pragma unroll
        for (int i = 0; i < 4; ++i) t += wsum[i];
        out[0] = (float)(t / TOTAL_ELEMS);
    }
}

extern "C" void kernel_launch(void* const* d_in, const int* in_sizes, int n_in,
                              void* d_out, int out_size, void* d_ws, size_t ws_size,
                              hipStream_t stream) {
    const float* src = (const float*)d_in[0];  // source_latent
    const float* edt = (const float*)d_in[1];  // edited_latent
    // d_in[2]/d_in[3] are the fixed Sobel kernels; baked into the math above
    // (flip-sign ambiguity is irrelevant under the magnitude).
    float* out     = (float*)d_out;
    float* partial = (float*)d_ws;             // NBLK floats = 8 KB, overwritten every call

    edge_loss_stage1<<<dim3(NBLK), dim3(TPB), 0, stream>>>(src, edt, partial);
    edge_loss_stage2<<<dim3(1), dim3(256), 0, stream>>>(partial, out, NBLK);
}